// Round 9
// baseline (587.864 us; speedup 1.0000x reference)
//
#include <hip/hip_runtime.h>
#include <hip/hip_bf16.h>
#include <cstdint>
#include <cstddef>

#define NN 1000
#define EE 128000
#define LAYERS 6
#define SCALE 0.125f
#define MAXDEG 320

typedef __attribute__((ext_vector_type(4))) float f32x4;
typedef __attribute__((ext_vector_type(8))) short short8v;

static __device__ __forceinline__ unsigned short f2bf(float x){
    unsigned int u = __float_as_uint(x);
    unsigned int lsb = (u >> 16) & 1u;
    u += 0x7fffu + lsb;
    return (unsigned short)(u >> 16);
}
static __device__ __forceinline__ float bf2f(unsigned short u){
    return __uint_as_float(((unsigned int)u) << 16);
}

// ---------------- sort-by-target (counting sort) ----------------
__global__ void zero_counts(int* cnt){
    cnt[threadIdx.x] = 0;
}

__global__ void hist_kernel(const int* __restrict__ tgt, int* cnt){
    int e = blockIdx.x*256 + threadIdx.x;
    if (e < EE) atomicAdd(&cnt[tgt[e]], 1);
}

__global__ void scan_kernel(const int* __restrict__ cnt, int* offs, int* cursor){
    __shared__ int s[1024];
    int tid = threadIdx.x;
    s[tid] = (tid < NN) ? cnt[tid] : 0;
    __syncthreads();
    for (int st = 1; st < 1024; st <<= 1){
        int v = (tid >= st) ? s[tid-st] : 0;
        __syncthreads();
        s[tid] += v;
        __syncthreads();
    }
    int excl = (tid == 0) ? 0 : s[tid-1];
    if (tid < NN){ offs[tid] = excl; cursor[tid] = excl; }
    if (tid == 0) offs[NN] = s[NN-1];
}

__global__ void scatter_kernel(const int* __restrict__ src, const int* __restrict__ tgt,
                               int* cursor, int* ssrc, int* epos){
    int e = blockIdx.x*256 + threadIdx.x;
    if (e < EE){
        int t = tgt[e];
        int pos = atomicAdd(&cursor[t], 1);
        ssrc[pos] = src[e];
        epos[e] = pos;
    }
}

// ---------------- edge encoder: 4 -> 16 -> 32, bf16 out, sorted order ----------------
__global__ __launch_bounds__(256) void edge_enc(
    const float* __restrict__ edge_attr,
    const float* __restrict__ w1, const float* __restrict__ b1,
    const float* __restrict__ w2, const float* __restrict__ b2,
    const int* __restrict__ epos,
    unsigned short* __restrict__ efs)
{
    __shared__ float w1s[64], b1s[16], w2s[512], b2s[32];
    int tid = threadIdx.x;
    if (tid < 64) w1s[tid] = w1[tid];
    if (tid < 16) b1s[tid] = b1[tid];
    if (tid < 32) b2s[tid] = b2[tid];
    w2s[tid] = w2[tid];
    w2s[tid+256] = w2[tid+256];
    __syncthreads();
    int e = blockIdx.x*256 + tid;
    if (e >= EE) return;
    float4 av = *(const float4*)(edge_attr + (size_t)e*4);
    float hd[16];
    #pragma unroll
    for (int i = 0; i < 16; i++){
        float v = av.x*w1s[i] + av.y*w1s[16+i] + av.z*w1s[32+i] + av.w*w1s[48+i] + b1s[i];
        hd[i] = fmaxf(v, 0.f);
    }
    unsigned short* op = efs + (size_t)epos[e]*32;
    #pragma unroll
    for (int k4 = 0; k4 < 8; k4++){
        ushort4 ub;
        float v0 = b2s[k4*4+0], v1 = b2s[k4*4+1], v2 = b2s[k4*4+2], v3 = b2s[k4*4+3];
        #pragma unroll
        for (int i = 0; i < 16; i++){
            float hv = hd[i];
            v0 += hv*w2s[i*32 + k4*4+0];
            v1 += hv*w2s[i*32 + k4*4+1];
            v2 += hv*w2s[i*32 + k4*4+2];
            v3 += hv*w2s[i*32 + k4*4+3];
        }
        ub.x = f2bf(v0); ub.y = f2bf(v1); ub.z = f2bf(v2); ub.w = f2bf(v3);
        *(ushort4*)(op + k4*4) = ub;
    }
}

// ---------------- merged conversions ----------------
__global__ __launch_bounds__(256) void convert_all(
    const float* __restrict__ Wq, const float* __restrict__ Wk,
    const float* __restrict__ Wv, const float* __restrict__ Ws,
    const float* __restrict__ embed_w, const float* __restrict__ x,
    unsigned short* __restrict__ Wt, unsigned short* __restrict__ ewt,
    unsigned short* __restrict__ xb)
{
    int bid = blockIdx.x;
    int tid = threadIdx.x;
    if (bid < 6144){
        int mm = bid >> 8;
        int tile = bid & 255;
        int tk = tile >> 4, tn = tile & 15;
        int l = mm >> 2, m = mm & 3;
        const float* W = ((m==0)?Wq:(m==1)?Wk:(m==2)?Wv:Ws) + (size_t)l*512*512;
        unsigned short* dst = Wt + (size_t)mm*512*512;
        __shared__ float ts[32][33];
        int r = tid >> 3, c0 = (tid & 7)*4;
        float4 v = *(const float4*)(W + (size_t)(tk*32 + r)*512 + tn*32 + c0);
        ts[r][c0+0] = v.x; ts[r][c0+1] = v.y; ts[r][c0+2] = v.z; ts[r][c0+3] = v.w;
        __syncthreads();
        ushort4 o;
        o.x = f2bf(ts[c0+0][r]); o.y = f2bf(ts[c0+1][r]);
        o.z = f2bf(ts[c0+2][r]); o.w = f2bf(ts[c0+3][r]);
        *(ushort4*)(dst + (size_t)(tn*32 + r)*512 + tk*32 + c0) = o;
    } else if (bid < 6144 + 128){
        int tile = bid - 6144;
        int tn = tile & 15, tk = tile >> 4;
        __shared__ float ts2[32][33];
        int r = tid >> 3, c0 = (tid & 7)*4;
        float4 v = *(const float4*)(embed_w + (size_t)(tk*32 + r)*512 + tn*32 + c0);
        ts2[r][c0+0] = v.x; ts2[r][c0+1] = v.y; ts2[r][c0+2] = v.z; ts2[r][c0+3] = v.w;
        __syncthreads();
        ushort4 o;
        o.x = f2bf(ts2[c0+0][r]); o.y = f2bf(ts2[c0+1][r]);
        o.z = f2bf(ts2[c0+2][r]); o.w = f2bf(ts2[c0+3][r]);
        *(ushort4*)(ewt + (size_t)(tn*32 + r)*256 + tk*32 + c0) = o;
    } else {
        int row = bid - 6144 - 128;
        xb[(size_t)row*256 + tid] = (row < NN) ? f2bf(x[(size_t)row*256 + tid]) : (unsigned short)0;
    }
}

// ---------------- MFMA embed GEMM ----------------
__global__ __launch_bounds__(256) void gemm_embed_mfma(
    const unsigned short* __restrict__ xb,
    const unsigned short* __restrict__ ewt,
    const float* __restrict__ bias, const float* __restrict__ pe,
    float* __restrict__ C, unsigned short* __restrict__ hb)
{
    int bid = blockIdx.x;
    int mt = bid >> 2, nt = bid & 3;
    int row0 = mt*64, col0 = nt*128;

    __shared__ __align__(16) unsigned short As[64*40];
    __shared__ __align__(16) unsigned short Bs[128*40];

    int tid = threadIdx.x;
    int wid = tid >> 6, l = tid & 63;
    int wm = wid >> 1, wn = wid & 1;

    f32x4 acc[2][4] = {};
    int ar = tid >> 2, akq = tid & 3;
    for (int k0 = 0; k0 < 256; k0 += 32){
        *(uint4*)&As[ar*40 + akq*8]      = *(const uint4*)&xb[(size_t)(row0+ar)*256 + k0 + akq*8];
        *(uint4*)&Bs[ar*40 + akq*8]      = *(const uint4*)&ewt[(size_t)(col0+ar)*256 + k0 + akq*8];
        *(uint4*)&Bs[(ar+64)*40 + akq*8] = *(const uint4*)&ewt[(size_t)(col0+ar+64)*256 + k0 + akq*8];
        __syncthreads();
        short8v a0 = *(const short8v*)&As[(wm*32 + (l&15))*40 + (l>>4)*8];
        short8v a1 = *(const short8v*)&As[(wm*32 + 16 + (l&15))*40 + (l>>4)*8];
        #pragma unroll
        for (int nj = 0; nj < 4; nj++){
            short8v b = *(const short8v*)&Bs[(wn*64 + nj*16 + (l&15))*40 + (l>>4)*8];
            acc[0][nj] = __builtin_amdgcn_mfma_f32_16x16x32_bf16(a0, b, acc[0][nj], 0, 0, 0);
            acc[1][nj] = __builtin_amdgcn_mfma_f32_16x16x32_bf16(a1, b, acc[1][nj], 0, 0, 0);
        }
        __syncthreads();
    }
    int rbase = (l >> 4)*4, cl = l & 15;
    #pragma unroll
    for (int mi = 0; mi < 2; mi++)
        #pragma unroll
        for (int nj = 0; nj < 4; nj++)
            #pragma unroll
            for (int r = 0; r < 4; r++){
                int grow = row0 + wm*32 + mi*16 + rbase + r;
                int gcol = col0 + wn*64 + nj*16 + cl;
                if (grow < NN){
                    float v = acc[mi][nj][r] + bias[gcol] + pe[(size_t)grow*512 + gcol];
                    C[(size_t)grow*512 + gcol] = v;
                    hb[(size_t)grow*512 + gcol] = f2bf(v);
                }
            }
}

// ---------------- bf16 MFMA GEMM, 64x64 tiles, LDS double-buffer + deep prefetch ----------------
__global__ __launch_bounds__(256) void gemm_qkvs_mfma(
    const unsigned short* __restrict__ hb,
    const unsigned short* __restrict__ Wt,
    const float* __restrict__ qb, const float* __restrict__ kb,
    const float* __restrict__ vb, const float* __restrict__ sb,
    float* __restrict__ Q, unsigned short* __restrict__ K16,
    unsigned short* __restrict__ V16, float* __restrict__ S)
{
    int bid = blockIdx.x;
    int mat = bid >> 7;
    int rem = bid & 127;
    int mt = rem >> 3, nt = rem & 7;
    int row0 = mt*64, col0 = nt*64;
    const unsigned short* W = Wt + (size_t)mat*512*512;
    const float* bias = (mat==0)?qb:(mat==1)?kb:(mat==2)?vb:sb;

    __shared__ __align__(16) unsigned short As[2][64*72];
    __shared__ __align__(16) unsigned short Bs[2][64*72];

    int tid = threadIdx.x;
    int wid = tid >> 6, l = tid & 63;
    int wm = wid >> 1, wn = wid & 1;

    f32x4 acc[2][2] = {};
    int lr = tid >> 2;
    int lc = (tid & 3)*2;                 // chunk index (8-ushort chunks): 0,2,4,6
    const unsigned short* ga = hb + (size_t)(row0+lr)*512 + lc*8;
    const unsigned short* gb = W  + (size_t)(col0+lr)*512 + lc*8;

    // prologue: tile0 -> LDS buf0 ; tile1 -> regs
    uint4 ra0 = *(const uint4*)(ga);
    uint4 ra1 = *(const uint4*)(ga + 8);
    uint4 rb0 = *(const uint4*)(gb);
    uint4 rb1 = *(const uint4*)(gb + 8);
    *(uint4*)&As[0][lr*72 + lc*8]     = ra0;
    *(uint4*)&As[0][lr*72 + lc*8 + 8] = ra1;
    *(uint4*)&Bs[0][lr*72 + lc*8]     = rb0;
    *(uint4*)&Bs[0][lr*72 + lc*8 + 8] = rb1;
    ra0 = *(const uint4*)(ga + 64);
    ra1 = *(const uint4*)(ga + 72);
    rb0 = *(const uint4*)(gb + 64);
    rb1 = *(const uint4*)(gb + 72);
    __syncthreads();

    #pragma unroll
    for (int t = 0; t < 8; t++){
        int cur = t & 1;
        // read fragments of current tile
        short8v a0f[2], a1f[2], b0f[2], b1f[2];
        #pragma unroll
        for (int ks = 0; ks < 2; ks++){
            a0f[ks] = *(const short8v*)&As[cur][(wm*32 + (l&15))*72      + ks*32 + (l>>4)*8];
            a1f[ks] = *(const short8v*)&As[cur][(wm*32 + 16 + (l&15))*72 + ks*32 + (l>>4)*8];
            b0f[ks] = *(const short8v*)&Bs[cur][(wn*32 + (l&15))*72      + ks*32 + (l>>4)*8];
            b1f[ks] = *(const short8v*)&Bs[cur][(wn*32 + 16 + (l&15))*72 + ks*32 + (l>>4)*8];
        }
        // write NEXT tile into the other buffer (regs loaded 1 iter ago)
        if (t < 7){
            *(uint4*)&As[cur^1][lr*72 + lc*8]     = ra0;
            *(uint4*)&As[cur^1][lr*72 + lc*8 + 8] = ra1;
            *(uint4*)&Bs[cur^1][lr*72 + lc*8]     = rb0;
            *(uint4*)&Bs[cur^1][lr*72 + lc*8 + 8] = rb1;
        }
        // issue loads for tile t+2
        if (t + 2 < 8){
            int k2 = (t + 2)*64;
            ra0 = *(const uint4*)(ga + k2);
            ra1 = *(const uint4*)(ga + k2 + 8);
            rb0 = *(const uint4*)(gb + k2);
            rb1 = *(const uint4*)(gb + k2 + 8);
        }
        // MFMA on current tile
        #pragma unroll
        for (int ks = 0; ks < 2; ks++){
            acc[0][0] = __builtin_amdgcn_mfma_f32_16x16x32_bf16(a0f[ks], b0f[ks], acc[0][0], 0, 0, 0);
            acc[0][1] = __builtin_amdgcn_mfma_f32_16x16x32_bf16(a0f[ks], b1f[ks], acc[0][1], 0, 0, 0);
            acc[1][0] = __builtin_amdgcn_mfma_f32_16x16x32_bf16(a1f[ks], b0f[ks], acc[1][0], 0, 0, 0);
            acc[1][1] = __builtin_amdgcn_mfma_f32_16x16x32_bf16(a1f[ks], b1f[ks], acc[1][1], 0, 0, 0);
        }
        if (t < 7) __syncthreads();
    }

    int rbase = (l >> 4)*4, cl = l & 15;
    #pragma unroll
    for (int mi = 0; mi < 2; mi++)
        #pragma unroll
        for (int nj = 0; nj < 2; nj++)
            #pragma unroll
            for (int r = 0; r < 4; r++){
                int grow = row0 + wm*32 + mi*16 + rbase + r;
                int gcol = col0 + wn*32 + nj*16 + cl;
                if (grow < NN){
                    float v = acc[mi][nj][r] + bias[gcol];
                    if (mat == 0)      Q[(size_t)grow*512 + gcol] = v;
                    else if (mat == 1) K16[(size_t)grow*512 + gcol] = f2bf(v);
                    else if (mat == 2) V16[(size_t)grow*512 + gcol] = f2bf(v);
                    else               S[(size_t)grow*512 + gcol] = v;
                }
            }
}

// ------------- per-node attention (MFMA scores, no-max softmax) + skip + LayerNorm -------------
// 256 threads (4 waves), one block per node.
__global__ __launch_bounds__(256) void attn_mfma(
    const float* __restrict__ Qm, const unsigned short* __restrict__ Km,
    const unsigned short* __restrict__ Vm,
    const unsigned short* __restrict__ efs, const float* __restrict__ e_w_l,
    const int* __restrict__ ssrc, const int* __restrict__ offs,
    const float* __restrict__ SKm, const float* __restrict__ hcur,
    const float* __restrict__ ln_g_l, const float* __restrict__ ln_b_l,
    float* __restrict__ hnext, unsigned short* __restrict__ hbn)
{
    int tid = threadIdx.x;
    int t = blockIdx.x;

    __shared__ float q_s[512];
    __shared__ float qe_s[8*33];
    __shared__ __align__(16) unsigned short qb_s[512];
    __shared__ __align__(16) unsigned short qbd_s[16*64*8];   // B-frag table, 16 k-steps
    __shared__ float sc_s[MAXDEG*8];
    __shared__ int   src_s[MAXDEG];
    __shared__ float pv_s[4][512];
    __shared__ float pe_s[4][256];
    __shared__ float s_s[256];
    __shared__ float redd[32];
    __shared__ float d_s[8];
    __shared__ float lredA[4], lredB[4];

    {
        float v0 = Qm[(size_t)t*512 + tid];
        float v1 = Qm[(size_t)t*512 + 256 + tid];
        q_s[tid] = v0; q_s[256+tid] = v1;
        qb_s[tid] = f2bf(v0); qb_s[256+tid] = f2bf(v1);
    }
    __syncthreads();
    // qe[h][d] = q[h] . e_w[d, h*64..]
    {
        int hh = tid >> 5, dd = tid & 31;
        const float* wrow = e_w_l + (size_t)dd*512 + hh*64;
        const float* qh = q_s + hh*64;
        float a = 0.f;
        #pragma unroll
        for (int c = 0; c < 64; c++) a += qh[c]*wrow[c];
        qe_s[hh*33 + dd] = a;
    }
    // build B-frag table: qbd_s[ks][l][j] = ((l&15)==(ks>>1)) ? qb[ks*32+(l>>4)*8+j] : 0
    {
        const uint4 z4 = {0u,0u,0u,0u};
        #pragma unroll
        for (int it = 0; it < 4; it++){
            int idx = tid + it*256;          // idx = ks*64 + l
            int ks = idx >> 6, lq = idx & 63;
            int col = lq & 15;
            uint4 v = (col == (ks >> 1)) ? *(const uint4*)&qb_s[ks*32 + (lq>>4)*8] : z4;
            *(uint4*)&qbd_s[idx*8] = v;
        }
    }
    int start = offs[t], deg = offs[t+1] - start;
    __syncthreads();

    // ---- phase 1: scores via MFMA ----
    {
        int wv = tid >> 6, l = tid & 63;
        int arow = l & 15;
        int achk8 = (l >> 4)*8;
        // ef-step B frag from qe_s
        short8v bef;
        {
            int col = l & 15;
            #pragma unroll
            for (int j = 0; j < 8; j++){
                float v = (col < 8) ? qe_s[col*33 + achk8 + j] : 0.f;
                bef[j] = (short)f2bf(v);
            }
        }
        for (int eg = wv*16; eg < deg; eg += 64){
            int e = eg + arow;
            int ec = (e < deg) ? e : 0;
            int s = ssrc[start + ec];
            if (achk8 == 0 && e < deg) src_s[e] = s;
            const unsigned short* kr = Km + (size_t)s*512 + achk8;
            f32x4 accA = {0.f, 0.f, 0.f, 0.f};
            f32x4 accB = {0.f, 0.f, 0.f, 0.f};
            #pragma unroll
            for (int ks = 0; ks < 8; ks++){
                short8v a = *(const short8v*)(kr + ks*32);
                short8v b = *(const short8v*)&qbd_s[(ks*64 + l)*8];
                accA = __builtin_amdgcn_mfma_f32_16x16x32_bf16(a, b, accA, 0, 0, 0);
            }
            #pragma unroll
            for (int ks = 8; ks < 16; ks++){
                short8v a = *(const short8v*)(kr + ks*32);
                short8v b = *(const short8v*)&qbd_s[(ks*64 + l)*8];
                accB = __builtin_amdgcn_mfma_f32_16x16x32_bf16(a, b, accB, 0, 0, 0);
            }
            {
                short8v a = *(const short8v*)(efs + (size_t)(start+ec)*32 + achk8);
                accA = __builtin_amdgcn_mfma_f32_16x16x32_bf16(a, bef, accA, 0, 0, 0);
            }
            #pragma unroll
            for (int r = 0; r < 4; r++){
                int er = eg + (l >> 4)*4 + r;
                if (arow < 8 && er < deg) sc_s[er*8 + arow] = (accA[r] + accB[r])*SCALE;
            }
        }
    }
    __syncthreads();

    // ---- exp + denominator (no max subtraction; scores are O(10), fp32-safe) ----
    {
        int he = tid & 7, ib = tid >> 3;
        float den = 0.f;
        for (int i = ib; i < deg; i += 32){
            float al = __expf(sc_s[i*8 + he]);
            sc_s[i*8 + he] = al;
            den += al;
        }
        den += __shfl_xor(den, 8);
        den += __shfl_xor(den, 16);
        den += __shfl_xor(den, 32);
        if ((tid & 63) < 8) redd[(tid>>6)*8 + (tid & 7)] = den;
    }
    __syncthreads();
    if (tid < 8) d_s[tid] = redd[tid] + redd[8+tid] + redd[16+tid] + redd[24+tid];
    __syncthreads();

    // ---- PV + ef accumulation: 4 waves, each covers full 512-ch V row, edges strided by 4 ----
    {
        int g = tid >> 6, q6 = tid & 63;
        int c8 = q6*8;                 // 8 V channels
        int h2 = q6 >> 3;              // head of those channels
        int dE4 = (q6 & 7)*4;          // 4 ef dims for head h2
        float accV[8] = {};
        float accE[4] = {};
        #pragma unroll 4
        for (int i = g; i < deg; i += 4){
            int s = src_s[i];
            float al = sc_s[i*8 + h2];
            short8v v = *(const short8v*)(Vm + (size_t)s*512 + c8);
            ushort4 e4 = *(const ushort4*)(efs + (size_t)(start+i)*32 + dE4);
            #pragma unroll
            for (int j = 0; j < 8; j++) accV[j] += al*bf2f((unsigned short)v[j]);
            accE[0] += al*bf2f(e4.x); accE[1] += al*bf2f(e4.y);
            accE[2] += al*bf2f(e4.z); accE[3] += al*bf2f(e4.w);
        }
        #pragma unroll
        for (int j = 0; j < 8; j++) pv_s[g][c8+j] = accV[j];
        *(float4*)&pe_s[g][h2*32 + dE4] = make_float4(accE[0], accE[1], accE[2], accE[3]);
    }
    __syncthreads();
    {
        float dv = d_s[tid >> 5];
        float invd = (dv > 0.f) ? 1.f/dv : 0.f;
        s_s[tid] = (pe_s[0][tid] + pe_s[1][tid] + pe_s[2][tid] + pe_s[3][tid]) * invd;
    }
    __syncthreads();

    // ---- output + skip + residual + LayerNorm ----
    {
        int c0 = tid, c1 = tid + 256;
        int h0 = c0 >> 6, h1 = c1 >> 6;
        float dv0 = d_s[h0], dv1 = d_s[h1];
        float i0 = (dv0 > 0.f) ? 1.f/dv0 : 0.f;
        float i1 = (dv1 > 0.f) ? 1.f/dv1 : 0.f;
        float r0 = (pv_s[0][c0] + pv_s[1][c0] + pv_s[2][c0] + pv_s[3][c0]) * i0;
        float r1 = (pv_s[0][c1] + pv_s[1][c1] + pv_s[2][c1] + pv_s[3][c1]) * i1;
        float oe0 = 0.f, oe1 = 0.f;
        const float* sp0 = s_s + h0*32;
        const float* sp1 = s_s + h1*32;
        #pragma unroll
        for (int d = 0; d < 32; d++){
            oe0 += sp0[d]*e_w_l[(size_t)d*512 + c0];
            oe1 += sp1[d]*e_w_l[(size_t)d*512 + c1];
        }
        float x0 = r0 + oe0 + SKm[(size_t)t*512 + c0] + hcur[(size_t)t*512 + c0];
        float x1 = r1 + oe1 + SKm[(size_t)t*512 + c1] + hcur[(size_t)t*512 + c1];

        float sA = x0 + x1, sB = x0*x0 + x1*x1;
        #pragma unroll
        for (int m2 = 1; m2 <= 32; m2 <<= 1){
            sA += __shfl_xor(sA, m2);
            sB += __shfl_xor(sB, m2);
        }
        int wv = tid >> 6, ln = tid & 63;
        if (ln == 0){ lredA[wv] = sA; lredB[wv] = sB; }
        __syncthreads();
        float tot  = lredA[0] + lredA[1] + lredA[2] + lredA[3];
        float tot2 = lredB[0] + lredB[1] + lredB[2] + lredB[3];
        float mu  = tot*(1.f/512.f);
        float var = tot2*(1.f/512.f) - mu*mu;
        float rstd = rsqrtf(var + 1e-5f);
        float y0 = (x0 - mu)*rstd*ln_g_l[c0] + ln_b_l[c0];
        float y1 = (x1 - mu)*rstd*ln_g_l[c1] + ln_b_l[c1];
        hnext[(size_t)t*512 + c0] = y0;
        hnext[(size_t)t*512 + c1] = y1;
        hbn[(size_t)t*512 + c0]   = f2bf(y0);
        hbn[(size_t)t*512 + c1]   = f2bf(y1);
    }
}

// ---------------- final head: dom + concat + MLP ----------------
__global__ __launch_bounds__(256) void final_head(
    const float* __restrict__ hin,
    const float* __restrict__ dom_w, const float* __restrict__ dom_b,
    const float* __restrict__ w1, const float* __restrict__ b1,
    const float* __restrict__ w2, const float* __restrict__ b2,
    float* __restrict__ out)
{
    int tid = threadIdx.x, t = blockIdx.x;
    __shared__ float h_s[512];
    __shared__ float dom_s[16];
    __shared__ float hid_s[256];
    __shared__ float red[256];
    h_s[tid]     = hin[(size_t)t*512 + tid];
    h_s[tid+256] = hin[(size_t)t*512 + 256 + tid];
    __syncthreads();
    if (tid < 16){
        float a = dom_b[tid];
        for (int i = 0; i < 512; i++) a += h_s[i]*dom_w[i*16 + tid];
        dom_s[tid] = a;
    }
    __syncthreads();
    float acc = b1[tid];
    for (int i = 0; i < 512; i++) acc += h_s[i]*w1[(size_t)i*256 + tid];
    #pragma unroll
    for (int i = 0; i < 16; i++) acc += dom_s[i]*w1[(size_t)(512+i)*256 + tid];
    hid_s[tid] = fmaxf(acc, 0.f);
    __syncthreads();
    int o = tid & 15, g = tid >> 4;
    float p = 0.f;
    #pragma unroll
    for (int j = 0; j < 16; j++) p += hid_s[g*16 + j]*w2[(g*16 + j)*16 + o];
    red[tid] = p;
    __syncthreads();
    if (tid < 16){
        float s2 = b2[tid];
        for (int gg = 0; gg < 16; gg++) s2 += red[gg*16 + tid];
        out[(size_t)t*16 + tid] = s2;
    }
}

// ---------------- launch ----------------
extern "C" void kernel_launch(void* const* d_in, const int* in_sizes, int n_in,
                              void* d_out, int out_size, void* d_ws, size_t ws_size,
                              hipStream_t stream)
{
    const float* x       = (const float*)d_in[0];
    const int*   eidx    = (const int*)  d_in[1];
    const float* eattr   = (const float*)d_in[2];
    const float* embed_w = (const float*)d_in[3];
    const float* embed_b = (const float*)d_in[4];
    const float* pe      = (const float*)d_in[5];
    const float* ee_w1   = (const float*)d_in[6];
    const float* ee_b1   = (const float*)d_in[7];
    const float* ee_w2   = (const float*)d_in[8];
    const float* ee_b2   = (const float*)d_in[9];
    const float* q_w     = (const float*)d_in[10];
    const float* q_b     = (const float*)d_in[11];
    const float* k_w     = (const float*)d_in[12];
    const float* k_b     = (const float*)d_in[13];
    const float* v_w     = (const float*)d_in[14];
    const float* v_b     = (const float*)d_in[15];
    const float* e_w     = (const float*)d_in[16];
    const float* skip_w  = (const float*)d_in[17];
    const float* skip_b  = (const float*)d_in[18];
    const float* ln_g    = (const float*)d_in[19];
    const float* ln_b    = (const float*)d_in[20];
    const float* dom_w   = (const float*)d_in[21];
    const float* dom_b   = (const float*)d_in[22];
    const float* cls_w1  = (const float*)d_in[23];
    const float* cls_b1  = (const float*)d_in[24];
    const float* cls_w2  = (const float*)d_in[25];
    const float* cls_b2  = (const float*)d_in[26];
    float* out = (float*)d_out;

    float* ws = (float*)d_ws;
    size_t o = 0;
    float* h0    = ws + o; o += (size_t)512*NN;
    float* h1    = ws + o; o += (size_t)512*NN;
    float* Qb    = ws + o; o += (size_t)512*NN;
    float* Sb    = ws + o; o += (size_t)512*NN;
    unsigned short* Kb16 = (unsigned short*)(ws + o); o += (size_t)1024*512/2;
    unsigned short* Vb16 = (unsigned short*)(ws + o); o += (size_t)1024*512/2;
    unsigned short* efs  = (unsigned short*)(ws + o); o += (size_t)EE*32/2;
    unsigned short* hb   = (unsigned short*)(ws + o); o += (size_t)1024*512/2;
    unsigned short* xb   = (unsigned short*)(ws + o); o += (size_t)1024*256/2;
    unsigned short* ewt  = (unsigned short*)(ws + o); o += (size_t)512*256/2;
    unsigned short* Wtb  = (unsigned short*)(ws + o); o += (size_t)24*512*512/2;
    int* cnt    = (int*)(ws + o); o += 1024;
    int* offs   = (int*)(ws + o); o += 1024;
    int* cursor = (int*)(ws + o); o += 1024;
    int* ssrc   = (int*)(ws + o); o += EE;
    int* epos   = (int*)(ws + o); o += EE;

    const int* srcp = eidx;
    const int* tgtp = eidx + EE;

    zero_counts<<<1, 1024, 0, stream>>>(cnt);
    hist_kernel<<<EE/256, 256, 0, stream>>>(tgtp, cnt);
    scan_kernel<<<1, 1024, 0, stream>>>(cnt, offs, cursor);
    scatter_kernel<<<EE/256, 256, 0, stream>>>(srcp, tgtp, cursor, ssrc, epos);
    edge_enc<<<EE/256, 256, 0, stream>>>(eattr, ee_w1, ee_b1, ee_w2, ee_b2, epos, efs);
    convert_all<<<6144 + 128 + 1024, 256, 0, stream>>>(q_w, k_w, v_w, skip_w, embed_w, x, Wtb, ewt, xb);
    gemm_embed_mfma<<<64, 256, 0, stream>>>(xb, ewt, embed_b, pe, h0, hb);

    float* hc = h0;
    float* hn = h1;
    for (int l = 0; l < LAYERS; l++){
        gemm_qkvs_mfma<<<512, 256, 0, stream>>>(
            hb, Wtb + (size_t)l*4*512*512,
            q_b + (size_t)l*512, k_b + (size_t)l*512,
            v_b + (size_t)l*512, skip_b + (size_t)l*512,
            Qb, Kb16, Vb16, Sb);
        attn_mfma<<<NN, 256, 0, stream>>>(
            Qb, Kb16, Vb16, efs, e_w + (size_t)l*32*512,
            ssrc, offs, Sb, hc,
            ln_g + (size_t)l*512, ln_b + (size_t)l*512,
            hn, hb);
        float* tmp = hc; hc = hn; hn = tmp;
    }
    final_head<<<NN, 256, 0, stream>>>(hc, dom_w, dom_b, cls_w1, cls_b1, cls_w2, cls_b2, out);
}